// Round 1
// baseline (600.948 us; speedup 1.0000x reference)
//
#include <hip/hip_runtime.h>
#include <hip/hip_cooperative_groups.h>
#include <stdint.h>

namespace cg = cooperative_groups;

#define HIDDEN 2560
#define NHEADS 8
#define HD 512
#define QDIM (NHEADS * HD)        // 4096
#define QKVROWS (QDIM + 2 * HD)   // 5120
#define SEQ 32768
#define NBLK 512
#define NWAVES (NBLK * 4)         // 2048 waves in grid
#define CHUNK (SEQ / NBLK)        // 64
#define PART_ST (8 + QDIM)        // 4104 floats per partial block
#define SCALE 0.044194173824159216f // 1/sqrt(512)

// ws layout (floats):
//   [0 .. 5120)      q[4096], k[512], v[512]
//   [8192 .. 12288)  attn
//   [16384 .. )      partials: NBLK x PART_ST (~8.4 MiB)
#define WS_QKV 0
#define WS_K   4096
#define WS_V   4608
#define WS_ATT 8192
#define WS_PART 16384

// Single persistent cooperative kernel: 512 blocks x 256 threads,
// 2 blocks/CU co-resident (VGPR ~150, LDS ~18.6 KB -> co-residency safe).
__global__ __launch_bounds__(256) void fused_decode(
    const float* __restrict__ x,
    const float* __restrict__ kvfull,
    const float* __restrict__ wq,
    const float* __restrict__ wk,
    const float* __restrict__ wv,
    const float* __restrict__ wo,
    const int* __restrict__ cur_pos,
    float* __restrict__ ws,
    float* __restrict__ out)
{
  cg::grid_group grid = cg::this_grid();
  const int tid = threadIdx.x;
  const int lane = tid & 63;
  const int wid = tid >> 6;
  const int bid = blockIdx.x;
  const int gwave = bid * 4 + wid;   // 0..2047

  __shared__ float sc[CHUNK][NHEADS];     // exp(score)
  __shared__ float4 vtmp[NHEADS][128];    // 16 KB combine buffer (phase 2C)
  __shared__ float fin[4][12];            // phase 3 cross-wave reduce

  // ---------------- phase 1: q/k/v GEMV (wave per row, grid-strided) ----------------
  for (int row = gwave; row < QKVROWS; row += NWAVES) {
    const float* w;
    if (row < QDIM) w = wq + (size_t)row * HIDDEN;
    else if (row < QDIM + HD) w = wk + (size_t)(row - QDIM) * HIDDEN;
    else w = wv + (size_t)(row - QDIM - HD) * HIDDEN;
    float acc = 0.f;
#pragma unroll
    for (int i = 0; i < 5; i++) {
      const int j = i * 512 + lane * 8;
      float4 a0 = *(const float4*)(w + j);
      float4 a1 = *(const float4*)(w + j + 4);
      float4 b0 = *(const float4*)(x + j);
      float4 b1 = *(const float4*)(x + j + 4);
      acc += a0.x * b0.x + a0.y * b0.y + a0.z * b0.z + a0.w * b0.w +
             a1.x * b1.x + a1.y * b1.y + a1.z * b1.z + a1.w * b1.w;
    }
#pragma unroll
    for (int off = 32; off > 0; off >>= 1) acc += __shfl_xor(acc, off);
    if (lane == 0) ws[WS_QKV + row] = acc;
  }

  __threadfence();
  grid.sync();

  // ---------------- phase 2: attention partials (block = 64-position chunk) ----------------
  {
    const int cur = cur_pos[0];
    const int s0 = bid * CHUNK;
    const float* K = kvfull;
    const float* V = kvfull + (size_t)SEQ * HD;
    float* pb = ws + WS_PART + (size_t)bid * PART_ST;

    // q fragments: lane holds q[h][lane*8 .. +8] for all 8 heads
    float qf[NHEADS][8];
#pragma unroll
    for (int h = 0; h < NHEADS; h++) {
      float4 a = *(const float4*)(ws + WS_QKV + h * HD + lane * 8);
      float4 b = *(const float4*)(ws + WS_QKV + h * HD + lane * 8 + 4);
      qf[h][0] = a.x; qf[h][1] = a.y; qf[h][2] = a.z; qf[h][3] = a.w;
      qf[h][4] = b.x; qf[h][5] = b.y; qf[h][6] = b.z; qf[h][7] = b.w;
    }

    // phase A: exp(scores); wave w handles 16 consecutive positions.
    // scores are O(1) -> exp without max subtraction is numerically safe.
    for (int ii = 0; ii < CHUNK / 4; ii++) {
      const int scix = wid * (CHUNK / 4) + ii;
      const int s = s0 + scix;
      const float* krow = (s == cur) ? (ws + WS_K) : (K + (size_t)s * HD);
      float4 a = *(const float4*)(krow + lane * 8);
      float4 b = *(const float4*)(krow + lane * 8 + 4);
      float kb[8] = {a.x, a.y, a.z, a.w, b.x, b.y, b.z, b.w};
      float p[NHEADS];
#pragma unroll
      for (int h = 0; h < NHEADS; h++) {
        float t = 0.f;
#pragma unroll
        for (int e = 0; e < 8; e++) t += kb[e] * qf[h][e];
        p[h] = t;
      }
#pragma unroll
      for (int off = 32; off > 0; off >>= 1) {
#pragma unroll
        for (int h = 0; h < NHEADS; h++) p[h] += __shfl_xor(p[h], off);
      }
      if (lane == 0) {
#pragma unroll
        for (int h = 0; h < NHEADS; h++) sc[scix][h] = __expf(p[h] * SCALE);
      }
    }
    __syncthreads();

    // den: per-head sum of exp
    if (tid < NHEADS) {
      float lsum = 0.f;
      for (int s = 0; s < CHUNK; s++) lsum += sc[s][tid];
      pb[tid] = lsum;
    }

    // phase C: num = sum exp(s)*V. 128 threads own 4 dims; 2 sy-halves (g)
    const int g = tid >> 7;      // 0,1
    const int tl = tid & 127;
    const int d0 = tl * 4;
    float4 acc[NHEADS];
#pragma unroll
    for (int h = 0; h < NHEADS; h++) acc[h] = make_float4(0.f, 0.f, 0.f, 0.f);
    for (int sy = g * (CHUNK / 2); sy < (g + 1) * (CHUNK / 2); sy++) {
      const int s = s0 + sy;
      const float* vrow = (s == cur) ? (ws + WS_V) : (V + (size_t)s * HD);
      float4 v4 = *(const float4*)(vrow + d0);
#pragma unroll
      for (int h = 0; h < NHEADS; h++) {
        const float pp = sc[sy][h];
        acc[h].x += pp * v4.x; acc[h].y += pp * v4.y;
        acc[h].z += pp * v4.z; acc[h].w += pp * v4.w;
      }
    }
    if (g == 1) {
#pragma unroll
      for (int h = 0; h < NHEADS; h++) vtmp[h][tl] = acc[h];
    }
    __syncthreads();
    if (g == 0) {
#pragma unroll
      for (int h = 0; h < NHEADS; h++) {
        float4 o = vtmp[h][tl];
        o.x += acc[h].x; o.y += acc[h].y; o.z += acc[h].z; o.w += acc[h].w;
        *(float4*)(pb + 8 + h * HD + d0) = o;
      }
    }
  }

  __threadfence();
  grid.sync();

  // ---------------- phase 3: combine partials. block handles 8 dims ----------------
  {
    const float* part = ws + WS_PART;
    const int gd0 = bid * 8;          // global dim base (0..4088), single head
    const int h = gd0 >> 9;
    const float* p0 = part + (size_t)tid * PART_ST;
    const float* p1 = p0 + (size_t)256 * PART_ST;
    float den = p0[h] + p1[h];
    float4 n0 = *(const float4*)(p0 + 8 + gd0);
    float4 n1 = *(const float4*)(p0 + 8 + gd0 + 4);
    float4 m0 = *(const float4*)(p1 + 8 + gd0);
    float4 m1 = *(const float4*)(p1 + 8 + gd0 + 4);
    n0.x += m0.x; n0.y += m0.y; n0.z += m0.z; n0.w += m0.w;
    n1.x += m1.x; n1.y += m1.y; n1.z += m1.z; n1.w += m1.w;
#pragma unroll
    for (int off = 32; off > 0; off >>= 1) {
      den  += __shfl_xor(den, off);
      n0.x += __shfl_xor(n0.x, off); n0.y += __shfl_xor(n0.y, off);
      n0.z += __shfl_xor(n0.z, off); n0.w += __shfl_xor(n0.w, off);
      n1.x += __shfl_xor(n1.x, off); n1.y += __shfl_xor(n1.y, off);
      n1.z += __shfl_xor(n1.z, off); n1.w += __shfl_xor(n1.w, off);
    }
    if (lane == 0) {
      fin[wid][0] = n0.x; fin[wid][1] = n0.y; fin[wid][2] = n0.z; fin[wid][3] = n0.w;
      fin[wid][4] = n1.x; fin[wid][5] = n1.y; fin[wid][6] = n1.z; fin[wid][7] = n1.w;
      fin[wid][8] = den;
    }
    __syncthreads();
    if (tid < 9) {
      fin[0][tid] = fin[0][tid] + fin[1][tid] + fin[2][tid] + fin[3][tid];
    }
    __syncthreads();
    if (tid < 8) ws[WS_ATT + gd0 + tid] = fin[0][tid] / fin[0][8];
  }

  __threadfence();
  grid.sync();

  // ---------------- phase 4: output GEMV (wave per row, grid-strided) ----------------
  {
    const float* attn = ws + WS_ATT;
    for (int row = gwave; row < HIDDEN; row += NWAVES) {
      const float* w = wo + (size_t)row * QDIM;
      float acc = 0.f;
#pragma unroll
      for (int i = 0; i < 8; i++) {
        const int j = i * 512 + lane * 8;
        float4 w0 = *(const float4*)(w + j);
        float4 w1 = *(const float4*)(w + j + 4);
        float4 a0 = *(const float4*)(attn + j);
        float4 a1 = *(const float4*)(attn + j + 4);
        acc += w0.x * a0.x + w0.y * a0.y + w0.z * a0.z + w0.w * a0.w +
               w1.x * a1.x + w1.y * a1.y + w1.z * a1.z + w1.w * a1.w;
      }
#pragma unroll
      for (int off = 32; off > 0; off >>= 1) acc += __shfl_xor(acc, off);
      if (lane == 0) out[row] = acc;
    }
  }
}

extern "C" void kernel_launch(void* const* d_in, const int* in_sizes, int n_in,
                              void* d_out, int out_size, void* d_ws, size_t ws_size,
                              hipStream_t stream) {
  (void)in_sizes; (void)n_in; (void)out_size; (void)ws_size;
  const float* x      = (const float*)d_in[0];
  // d_in[1] = kv_sliding (unused by reference)
  const float* kvfull = (const float*)d_in[2];
  const float* wq     = (const float*)d_in[3];
  const float* wk     = (const float*)d_in[4];
  const float* wv     = (const float*)d_in[5];
  const float* wo     = (const float*)d_in[6];
  const int* cur_pos  = (const int*)d_in[7];
  // d_in[8] = ring_pos (unused by reference)
  float* out = (float*)d_out;
  float* ws  = (float*)d_ws;

  void* args[] = {(void*)&x, (void*)&kvfull, (void*)&wq, (void*)&wk, (void*)&wv,
                  (void*)&wo, (void*)&cur_pos, (void*)&ws, (void*)&out};
  hipLaunchCooperativeKernel((const void*)fused_decode, dim3(NBLK), dim3(256),
                             args, 0, stream);
}

// Round 4
// 286.660 us; speedup vs baseline: 2.0964x; 2.0964x over previous
//
#include <hip/hip_runtime.h>
#include <stdint.h>

#define HIDDEN 2560
#define NHEADS 8
#define HD 512
#define QDIM (NHEADS * HD)        // 4096
#define SEQ 32768
#define CHUNK 32
#define NCHUNK (SEQ / CHUNK)      // 1024
#define PART_ST (8 + NHEADS * HD) // 4104 floats per partial block: den[8] + num[8][512]
#define SCALE 0.044194173824159216f // 1/sqrt(512)

// ws layout (floats):
//   [0 .. 5120)      q[4096], k[512], v[512]
//   [8192 .. 12288)  attn
//   [16384 .. )      partials: NCHUNK x PART_ST  (~16.9 MiB; ws is 512 MiB)
#define WS_QKV 0
#define WS_K   4096
#define WS_V   4608
#define WS_ATT 8192
#define WS_PART 16384

// ---------------- kernel 1: q/k/v GEMV (wave per row) ----------------
__global__ __launch_bounds__(256) void qkv_gemv(
    const float* __restrict__ x,
    const float* __restrict__ wq,
    const float* __restrict__ wk,
    const float* __restrict__ wv,
    float* __restrict__ qkv) {
  const int row = blockIdx.x * 4 + (threadIdx.x >> 6);
  const int lane = threadIdx.x & 63;
  const float* w;
  if (row < QDIM) w = wq + (size_t)row * HIDDEN;
  else if (row < QDIM + HD) w = wk + (size_t)(row - QDIM) * HIDDEN;
  else w = wv + (size_t)(row - QDIM - HD) * HIDDEN;
  float acc = 0.f;
#pragma unroll
  for (int i = 0; i < 5; i++) {
    const int j = i * 512 + lane * 8;
    float4 a0 = *(const float4*)(w + j);
    float4 a1 = *(const float4*)(w + j + 4);
    float4 b0 = *(const float4*)(x + j);
    float4 b1 = *(const float4*)(x + j + 4);
    acc += a0.x * b0.x + a0.y * b0.y + a0.z * b0.z + a0.w * b0.w +
           a1.x * b1.x + a1.y * b1.y + a1.z * b1.z + a1.w * b1.w;
  }
#pragma unroll
  for (int off = 32; off > 0; off >>= 1) acc += __shfl_xor(acc, off);
  if (lane == 0) qkv[row] = acc;
}

// ---------- kernel 2: attention partials ----------
// 1024 blocks x 256 threads (CHUNK=32). No forced occupancy bound — let the
// allocator pick; grid size alone provides 4 blocks/CU if registers permit.
// Phase A processes 2 positions at a time: 4 float4 loads in flight before
// the shuffle-reduce chain.
__global__ __launch_bounds__(256) void attn_partial(
    const float* __restrict__ kvfull,
    const float* __restrict__ ws,
    const int* __restrict__ cur_pos,
    float* __restrict__ part) {
  __shared__ float sc[CHUNK][NHEADS];      // exp(score)
  __shared__ float4 vtmp[NHEADS][128];     // 16 KB combine buffer for phase C
  const int tid = threadIdx.x;
  const int lane = tid & 63;
  const int wid = tid >> 6;
  const int cur = cur_pos[0];
  const int s0 = blockIdx.x * CHUNK;
  const float* K = kvfull;
  const float* V = kvfull + (size_t)SEQ * HD;

  // q fragments: lane holds q[h][lane*8 .. +8] for all 8 heads
  float qf[NHEADS][8];
#pragma unroll
  for (int h = 0; h < NHEADS; h++) {
    float4 a = *(const float4*)(ws + WS_QKV + h * HD + lane * 8);
    float4 b = *(const float4*)(ws + WS_QKV + h * HD + lane * 8 + 4);
    qf[h][0] = a.x; qf[h][1] = a.y; qf[h][2] = a.z; qf[h][3] = a.w;
    qf[h][4] = b.x; qf[h][5] = b.y; qf[h][6] = b.z; qf[h][7] = b.w;
  }

  // phase A: exp(scores). wave w handles 8 consecutive positions, 2 per iter.
  // scores are O(1) -> exp without max subtraction is numerically safe.
  for (int ii = 0; ii < 4; ii++) {
    const int sx = wid * 8 + ii * 2;
    const int sA = s0 + sx;
    const int sB = sA + 1;
    const float* krA = (sA == cur) ? (ws + WS_K) : (K + (size_t)sA * HD);
    const float* krB = (sB == cur) ? (ws + WS_K) : (K + (size_t)sB * HD);
    float4 a0 = *(const float4*)(krA + lane * 8);
    float4 a1 = *(const float4*)(krA + lane * 8 + 4);
    float4 b0 = *(const float4*)(krB + lane * 8);
    float4 b1 = *(const float4*)(krB + lane * 8 + 4);
    float kA[8] = {a0.x, a0.y, a0.z, a0.w, a1.x, a1.y, a1.z, a1.w};
    float kB[8] = {b0.x, b0.y, b0.z, b0.w, b1.x, b1.y, b1.z, b1.w};
    float pA[NHEADS], pB[NHEADS];
#pragma unroll
    for (int h = 0; h < NHEADS; h++) {
      float tA = 0.f, tB = 0.f;
#pragma unroll
      for (int e = 0; e < 8; e++) {
        tA += kA[e] * qf[h][e];
        tB += kB[e] * qf[h][e];
      }
      pA[h] = tA; pB[h] = tB;
    }
#pragma unroll
    for (int off = 32; off > 0; off >>= 1) {
#pragma unroll
      for (int h = 0; h < NHEADS; h++) {
        pA[h] += __shfl_xor(pA[h], off);
        pB[h] += __shfl_xor(pB[h], off);
      }
    }
    if (lane == 0) {
#pragma unroll
      for (int h = 0; h < NHEADS; h++) {
        sc[sx][h]     = __expf(pA[h] * SCALE);
        sc[sx + 1][h] = __expf(pB[h] * SCALE);
      }
    }
  }
  __syncthreads();

  // den: per-head sum of exp
  float* pb = part + (size_t)blockIdx.x * PART_ST;
  if (tid < NHEADS) {
    float lsum = 0.f;
    for (int s = 0; s < CHUNK; s++) lsum += sc[s][tid];
    pb[tid] = lsum;
  }

  // phase C: num = sum exp(s)*V. 128 threads own 4 dims; 2 sy-halves (g)
  const int g = tid >> 7;      // 0,1
  const int tl = tid & 127;
  const int d0 = tl * 4;
  float4 acc[NHEADS];
#pragma unroll
  for (int h = 0; h < NHEADS; h++) acc[h] = make_float4(0.f, 0.f, 0.f, 0.f);
  for (int sy = g * (CHUNK / 2); sy < (g + 1) * (CHUNK / 2); sy++) {
    const int s = s0 + sy;
    const float* vrow = (s == cur) ? (ws + WS_V) : (V + (size_t)s * HD);
    float4 v4 = *(const float4*)(vrow + d0);
#pragma unroll
    for (int h = 0; h < NHEADS; h++) {
      const float pp = sc[sy][h];
      acc[h].x += pp * v4.x; acc[h].y += pp * v4.y;
      acc[h].z += pp * v4.z; acc[h].w += pp * v4.w;
    }
  }
  if (g == 1) {
#pragma unroll
    for (int h = 0; h < NHEADS; h++) vtmp[h][tl] = acc[h];
  }
  __syncthreads();
  if (g == 0) {
#pragma unroll
    for (int h = 0; h < NHEADS; h++) {
      float4 o = vtmp[h][tl];
      o.x += acc[h].x; o.y += acc[h].y; o.z += acc[h].z; o.w += acc[h].w;
      *(float4*)(pb + 8 + h * HD + d0) = o;
    }
  }
}

// ---------------- kernel 3: combine partials (pure sum, no rescale) ----------------
__global__ __launch_bounds__(256) void attn_reduce(
    const float* __restrict__ part,
    float* __restrict__ attn) {
  const int h = blockIdx.x >> 4;       // 8 heads
  const int dgrp = blockIdx.x & 15;    // 16 groups of 32 dims
  const int tid = threadIdx.x;
  __shared__ float red[256];
  __shared__ float pacc[8][32];

  float dsum = 0.f;
#pragma unroll
  for (int k = 0; k < 4; k++)
    dsum += part[(size_t)(tid + k * 256) * PART_ST + h];
  red[tid] = dsum;
  __syncthreads();
  for (int off = 128; off > 0; off >>= 1) {
    if (tid < off) red[tid] += red[tid + off];
    __syncthreads();
  }
  const float Linv = 1.f / red[0];

  const int dloc = tid & 31;
  const int bs = tid >> 5;             // 8 b-groups of 128
  const int d = dgrp * 32 + dloc;
  float acc = 0.f;
#pragma unroll 8
  for (int b = bs * (NCHUNK / 8); b < (bs + 1) * (NCHUNK / 8); b++) {
    acc += part[(size_t)b * PART_ST + 8 + h * HD + d];
  }
  pacc[bs][dloc] = acc;
  __syncthreads();
  if (tid < 32) {
    float s = ((pacc[0][tid] + pacc[1][tid]) + (pacc[2][tid] + pacc[3][tid])) +
              ((pacc[4][tid] + pacc[5][tid]) + (pacc[6][tid] + pacc[7][tid]));
    attn[h * HD + dgrp * 32 + tid] = s * Linv;
  }
}

// ---------------- kernel 4: output GEMV (wave per row) ----------------
__global__ __launch_bounds__(256) void out_gemv(
    const float* __restrict__ wo,
    const float* __restrict__ attn,
    float* __restrict__ out) {
  const int row = blockIdx.x * 4 + (threadIdx.x >> 6);
  const int lane = threadIdx.x & 63;
  const float* w = wo + (size_t)row * QDIM;
  float acc = 0.f;
#pragma unroll
  for (int i = 0; i < 8; i++) {
    const int j = i * 512 + lane * 8;
    float4 w0 = *(const float4*)(w + j);
    float4 w1 = *(const float4*)(w + j + 4);
    float4 a0 = *(const float4*)(attn + j);
    float4 a1 = *(const float4*)(attn + j + 4);
    acc += w0.x * a0.x + w0.y * a0.y + w0.z * a0.z + w0.w * a0.w +
           w1.x * a1.x + w1.y * a1.y + w1.z * a1.z + w1.w * a1.w;
  }
#pragma unroll
  for (int off = 32; off > 0; off >>= 1) acc += __shfl_xor(acc, off);
  if (lane == 0) out[row] = acc;
}

extern "C" void kernel_launch(void* const* d_in, const int* in_sizes, int n_in,
                              void* d_out, int out_size, void* d_ws, size_t ws_size,
                              hipStream_t stream) {
  (void)in_sizes; (void)n_in; (void)out_size; (void)ws_size;
  const float* x      = (const float*)d_in[0];
  // d_in[1] = kv_sliding (unused by reference)
  const float* kvfull = (const float*)d_in[2];
  const float* wq     = (const float*)d_in[3];
  const float* wk     = (const float*)d_in[4];
  const float* wv     = (const float*)d_in[5];
  const float* wo     = (const float*)d_in[6];
  const int* cur_pos  = (const int*)d_in[7];
  // d_in[8] = ring_pos (unused by reference)
  float* out = (float*)d_out;
  float* ws = (float*)d_ws;

  qkv_gemv<<<(QDIM + 2 * HD) / 4, 256, 0, stream>>>(x, wq, wk, wv, ws + WS_QKV);
  attn_partial<<<NCHUNK, 256, 0, stream>>>(kvfull, ws, cur_pos, ws + WS_PART);
  attn_reduce<<<NHEADS * 16, 256, 0, stream>>>(ws + WS_PART, ws + WS_ATT);
  out_gemv<<<HIDDEN / 4, 256, 0, stream>>>(wo, ws + WS_ATT, out);
}